// Round 1
// baseline (1540.663 us; speedup 1.0000x reference)
//
#include <hip/hip_runtime.h>
#include <cstdint>
#include <cstddef>

#define N_NODES 32768
#define CIN 256
#define HDIM 512
#define COUT_F 256
#define NTYPE 4
#define ALIGN_SEG 128
#define NPAD (N_NODES + NTYPE * ALIGN_SEG)  // 33280
#define BN_EPS 1e-5f
#define SLOPE 0.01f

// ---------------- sorting machinery ----------------

__global__ void hist_kernel(const int* __restrict__ nt, int* __restrict__ blockHist) {
  __shared__ int h[NTYPE];
  int tid = threadIdx.x;
  if (tid < NTYPE) h[tid] = 0;
  __syncthreads();
  int i = blockIdx.x * 256 + tid;
  atomicAdd(&h[nt[i]], 1);
  __syncthreads();
  if (tid < NTYPE) blockHist[blockIdx.x * NTYPE + tid] = h[tid];
}

__global__ void scan_kernel(const int* __restrict__ blockHist, int* __restrict__ blockBase,
                            int* __restrict__ meta) {
  int tid = threadIdx.x;
  if (tid < NTYPE) {
    int run = 0;
    for (int b = 0; b < 128; ++b) {
      blockBase[b * NTYPE + tid] = run;
      run += blockHist[b * NTYPE + tid];
    }
    meta[tid] = run;  // per-type count
  }
  __syncthreads();
  if (tid == 0) {
    int s = 0;
    for (int t = 0; t < NTYPE; ++t) {
      meta[4 + t] = s;  // aligned segment start
      s += (meta[t] + ALIGN_SEG - 1) & ~(ALIGN_SEG - 1);
    }
    meta[8] = s;  // padded total
  }
}

// stable rank within 256-chunk -> deterministic permutation
__global__ void rank_scatter_kernel(const int* __restrict__ nt, const int* __restrict__ blockBase,
                                    const int* __restrict__ meta, int* __restrict__ perm) {
  __shared__ int st[256];
  int tid = threadIdx.x;
  int i = blockIdx.x * 256 + tid;
  int t = nt[i];
  st[tid] = t;
  __syncthreads();
  int rank = 0;
  for (int j = 0; j < tid; ++j) rank += (st[j] == t) ? 1 : 0;
  perm[meta[4 + t] + blockBase[blockIdx.x * NTYPE + t] + rank] = i;
}

// xs[p] = x[perm[p]] (zeros for padding rows). block = 64 threads (CIN/4 float4)
__global__ void gather_kernel(const float* __restrict__ x, const int* __restrict__ perm,
                              float* __restrict__ xs) {
  int p = blockIdx.x;
  int src = perm[p];
  float4* dst = (float4*)(xs + (size_t)p * CIN);
  if (src < 0) {
    dst[threadIdx.x] = make_float4(0.f, 0.f, 0.f, 0.f);
  } else {
    const float4* s = (const float4*)(x + (size_t)src * CIN);
    dst[threadIdx.x] = s[threadIdx.x];
  }
}

// ---------------- fp32 tiled GEMM ----------------
// TM=TN=64, TK=16, 256 threads, 4x4 microtile per thread.
// Segment starts are 128-aligned so every 64-row tile is single-type.

template <int K, int COUT, bool SCATTER>
__global__ __launch_bounds__(256) void gemm_kernel(
    const float* __restrict__ A,     // [NPAD][K]
    const float* __restrict__ W,     // [T][K][COUT]
    const float* __restrict__ bias,  // [T][COUT]
    float* __restrict__ Y,           // [NPAD][COUT] or d_out [N][COUT]
    const int* __restrict__ meta, const int* __restrict__ perm) {
  const int tn = blockIdx.x, tm = blockIdx.y;
  const int row0 = tm * 64, col0 = tn * 64;
  const int s1 = meta[5], s2 = meta[6], s3 = meta[7];
  const int t = row0 >= s3 ? 3 : (row0 >= s2 ? 2 : (row0 >= s1 ? 1 : 0));
  const float* __restrict__ Wt = W + (size_t)t * K * COUT;

  __shared__ __align__(16) float As[16][68];
  __shared__ __align__(16) float Bs[16][68];

  const int tid = threadIdx.x;
  const int rowA = tid >> 2, kA = (tid & 3) * 4;   // A tile load: 64 rows x 16 k
  const int kB = tid >> 4, colB = (tid & 15) * 4;  // B tile load: 16 k x 64 cols
  const int ty = tid >> 4, tx = tid & 15;          // compute coords

  float acc[4][4] = {};

  for (int k0 = 0; k0 < K; k0 += 16) {
    float4 a4 = *(const float4*)(A + (size_t)(row0 + rowA) * K + k0 + kA);
    float4 b4 = *(const float4*)(Wt + (size_t)(k0 + kB) * COUT + col0 + colB);
    As[kA + 0][rowA] = a4.x;
    As[kA + 1][rowA] = a4.y;
    As[kA + 2][rowA] = a4.z;
    As[kA + 3][rowA] = a4.w;
    *(float4*)&Bs[kB][colB] = b4;
    __syncthreads();
#pragma unroll
    for (int kk = 0; kk < 16; ++kk) {
      float4 av = *(const float4*)&As[kk][ty * 4];
      float4 bv = *(const float4*)&Bs[kk][tx * 4];
      float a[4] = {av.x, av.y, av.z, av.w};
      float b[4] = {bv.x, bv.y, bv.z, bv.w};
#pragma unroll
      for (int i = 0; i < 4; ++i)
#pragma unroll
        for (int j = 0; j < 4; ++j) acc[i][j] = fmaf(a[i], b[j], acc[i][j]);
    }
    __syncthreads();
  }

  float4 bb = *(const float4*)(bias + (size_t)t * COUT + col0 + tx * 4);
#pragma unroll
  for (int i = 0; i < 4; ++i) {
    int r = row0 + ty * 4 + i;
    float4 o = make_float4(acc[i][0] + bb.x, acc[i][1] + bb.y, acc[i][2] + bb.z,
                           acc[i][3] + bb.w);
    if (SCATTER) {
      int dst = perm[r];
      if (dst >= 0) *(float4*)(Y + (size_t)dst * COUT + col0 + tx * 4) = o;
    } else {
      *(float4*)(Y + (size_t)r * COUT + col0 + tx * 4) = o;
    }
  }
}

// ---------------- BN ----------------

__global__ __launch_bounds__(256) void bn_stats_kernel(const float* __restrict__ h,
                                                       const int* __restrict__ meta,
                                                       float* __restrict__ mean,
                                                       float* __restrict__ rstd) {
  const int t = blockIdx.y;
  const int lane = threadIdx.x & 63;
  const int rl = threadIdx.x >> 6;  // 0..3
  const int c = blockIdx.x * 64 + lane;
  const int start = meta[4 + t];
  const int cnt = meta[t];
  float s = 0.f, q = 0.f;
  for (int r = rl; r < cnt; r += 4) {
    float v = h[(size_t)(start + r) * HDIM + c];
    s += v;
    q += v * v;
  }
  __shared__ float redS[4][64], redQ[4][64];
  redS[rl][lane] = s;
  redQ[rl][lane] = q;
  __syncthreads();
  if (rl == 0) {
    float S = redS[0][lane] + redS[1][lane] + redS[2][lane] + redS[3][lane];
    float Q = redQ[0][lane] + redQ[1][lane] + redQ[2][lane] + redQ[3][lane];
    float n = (float)(cnt > 1 ? cnt : 1);
    float m = S / n;
    float var = Q / n - m * m;
    mean[t * HDIM + c] = m;
    rstd[t * HDIM + c] = rsqrtf(fmaxf(var, 0.f) + BN_EPS);
  }
}

__global__ __launch_bounds__(256) void bn_apply_kernel(
    float* __restrict__ h, const int* __restrict__ meta, const float* __restrict__ mean,
    const float* __restrict__ rstd, const float* __restrict__ gamma,
    const float* __restrict__ beta) {
  size_t idx = (size_t)blockIdx.x * 256 + threadIdx.x;  // float4 units
  int row = (int)(idx >> 7);  // HDIM/4 = 128 float4 per row
  int cq = (int)(idx & 127);
  const int s1 = meta[5], s2 = meta[6], s3 = meta[7];
  const int t = row >= s3 ? 3 : (row >= s2 ? 2 : (row >= s1 ? 1 : 0));
  float4 v = *(float4*)(h + (size_t)row * HDIM + cq * 4);
  float4 m = *(const float4*)(mean + t * HDIM + cq * 4);
  float4 r = *(const float4*)(rstd + t * HDIM + cq * 4);
  float4 g = *(const float4*)(gamma + (size_t)t * HDIM + cq * 4);
  float4 b = *(const float4*)(beta + (size_t)t * HDIM + cq * 4);
  float o0 = (v.x - m.x) * r.x * g.x + b.x;
  float o1 = (v.y - m.y) * r.y * g.y + b.y;
  float o2 = (v.z - m.z) * r.z * g.z + b.z;
  float o3 = (v.w - m.w) * r.w * g.w + b.w;
  o0 = o0 >= 0.f ? o0 : SLOPE * o0;
  o1 = o1 >= 0.f ? o1 : SLOPE * o1;
  o2 = o2 >= 0.f ? o2 : SLOPE * o2;
  o3 = o3 >= 0.f ? o3 : SLOPE * o3;
  *(float4*)(h + (size_t)row * HDIM + cq * 4) = make_float4(o0, o1, o2, o3);
}

// ---------------- launch ----------------

extern "C" void kernel_launch(void* const* d_in, const int* in_sizes, int n_in, void* d_out,
                              int out_size, void* d_ws, size_t ws_size, hipStream_t stream) {
  const float* x = (const float*)d_in[0];
  const int* nt = (const int*)d_in[1];
  const float* W1 = (const float*)d_in[2];
  const float* b1 = (const float*)d_in[3];
  const float* W2 = (const float*)d_in[4];
  const float* b2 = (const float*)d_in[5];
  const float* W3 = (const float*)d_in[6];
  const float* b3 = (const float*)d_in[7];
  const float* g1 = (const float*)d_in[8];
  const float* be1 = (const float*)d_in[9];
  const float* g2 = (const float*)d_in[10];
  const float* be2 = (const float*)d_in[11];
  float* out = (float*)d_out;

  char* ws = (char*)d_ws;
  size_t off = 0;
  auto alloc = [&](size_t bytes) {
    void* p = ws + off;
    off = (off + bytes + 255) & ~(size_t)255;
    return p;
  };
  int* meta = (int*)alloc(16 * 4);
  int* blockHist = (int*)alloc(128 * NTYPE * 4);
  int* blockBase = (int*)alloc(128 * NTYPE * 4);
  int* perm = (int*)alloc((size_t)NPAD * 4);
  float* mean = (float*)alloc((size_t)NTYPE * HDIM * 4);
  float* rstd = (float*)alloc((size_t)NTYPE * HDIM * 4);
  float* bufA = (float*)alloc((size_t)NPAD * HDIM * 4);
  float* bufB = (float*)alloc((size_t)NPAD * HDIM * 4);
  float* xs = bufA;  // [NPAD][CIN]  (first half of bufA)
  float* h1 = bufB;  // [NPAD][HDIM]
  float* h2 = bufA;  // [NPAD][HDIM] (xs is dead by then)

  hipMemsetAsync(meta, 0, 64, stream);
  hipMemsetAsync(perm, 0xFF, (size_t)NPAD * 4, stream);
  hist_kernel<<<128, 256, 0, stream>>>(nt, blockHist);
  scan_kernel<<<1, 64, 0, stream>>>(blockHist, blockBase, meta);
  rank_scatter_kernel<<<128, 256, 0, stream>>>(nt, blockBase, meta, perm);
  gather_kernel<<<NPAD, 64, 0, stream>>>(x, perm, xs);

  gemm_kernel<CIN, HDIM, false>
      <<<dim3(HDIM / 64, NPAD / 64), 256, 0, stream>>>(xs, W1, b1, h1, meta, nullptr);
  bn_stats_kernel<<<dim3(HDIM / 64, NTYPE), 256, 0, stream>>>(h1, meta, mean, rstd);
  bn_apply_kernel<<<(NPAD * (HDIM / 4)) / 256, 256, 0, stream>>>(h1, meta, mean, rstd, g1, be1);

  gemm_kernel<HDIM, HDIM, false>
      <<<dim3(HDIM / 64, NPAD / 64), 256, 0, stream>>>(h1, W2, b2, h2, meta, nullptr);
  bn_stats_kernel<<<dim3(HDIM / 64, NTYPE), 256, 0, stream>>>(h2, meta, mean, rstd);
  bn_apply_kernel<<<(NPAD * (HDIM / 4)) / 256, 256, 0, stream>>>(h2, meta, mean, rstd, g2, be2);

  gemm_kernel<HDIM, COUT_F, true>
      <<<dim3(COUT_F / 64, NPAD / 64), 256, 0, stream>>>(h2, W3, b3, out, meta, perm);
}

// Round 2
// 592.362 us; speedup vs baseline: 2.6009x; 2.6009x over previous
//
#include <hip/hip_runtime.h>
#include <cstdint>
#include <cstddef>

#define N_NODES 32768
#define CIN 256
#define HDIM 512
#define COUT_F 256
#define NTYPE 4
#define ALIGN_SEG 128
#define NPAD (N_NODES + NTYPE * ALIGN_SEG)  // 33280
#define BN_EPS 1e-5f
#define SLOPE 0.01f
#define NCHUNK 64

// ---------------- sorting machinery ----------------

__global__ void hist_kernel(const int* __restrict__ nt, int* __restrict__ blockHist) {
  __shared__ int h[NTYPE];
  int tid = threadIdx.x;
  if (tid < NTYPE) h[tid] = 0;
  __syncthreads();
  int i = blockIdx.x * 256 + tid;
  atomicAdd(&h[nt[i]], 1);
  __syncthreads();
  if (tid < NTYPE) blockHist[blockIdx.x * NTYPE + tid] = h[tid];
}

__global__ void scan_kernel(const int* __restrict__ blockHist, int* __restrict__ blockBase,
                            int* __restrict__ meta) {
  int tid = threadIdx.x;
  if (tid < NTYPE) {
    int run = 0;
    for (int b = 0; b < 128; ++b) {
      blockBase[b * NTYPE + tid] = run;
      run += blockHist[b * NTYPE + tid];
    }
    meta[tid] = run;  // per-type count
  }
  __syncthreads();
  if (tid == 0) {
    int s = 0;
    for (int t = 0; t < NTYPE; ++t) {
      meta[4 + t] = s;  // aligned segment start
      s += (meta[t] + ALIGN_SEG - 1) & ~(ALIGN_SEG - 1);
    }
    meta[8] = s;  // padded total
  }
}

// stable rank within 256-chunk -> deterministic permutation
__global__ void rank_scatter_kernel(const int* __restrict__ nt, const int* __restrict__ blockBase,
                                    const int* __restrict__ meta, int* __restrict__ perm) {
  __shared__ int st[256];
  int tid = threadIdx.x;
  int i = blockIdx.x * 256 + tid;
  int t = nt[i];
  st[tid] = t;
  __syncthreads();
  int rank = 0;
  for (int j = 0; j < tid; ++j) rank += (st[j] == t) ? 1 : 0;
  perm[meta[4 + t] + blockBase[blockIdx.x * NTYPE + t] + rank] = i;
}

// xs[p] = x[perm[p]] (zeros for padding rows). block = 64 threads (CIN/4 float4)
__global__ void gather_kernel(const float* __restrict__ x, const int* __restrict__ perm,
                              float* __restrict__ xs) {
  int p = blockIdx.x;
  int src = perm[p];
  float4* dst = (float4*)(xs + (size_t)p * CIN);
  if (src < 0) {
    dst[threadIdx.x] = make_float4(0.f, 0.f, 0.f, 0.f);
  } else {
    const float4* s = (const float4*)(x + (size_t)src * CIN);
    dst[threadIdx.x] = s[threadIdx.x];
  }
}

// ---------------- fp32 tiled GEMM ----------------
// TM=TN=64, TK=16, 256 threads, 4x4 microtile per thread.
// Segment starts are 128-aligned so every 64-row tile is single-type.

template <int K, int COUT, bool SCATTER>
__global__ __launch_bounds__(256) void gemm_kernel(
    const float* __restrict__ A,     // [NPAD][K]
    const float* __restrict__ W,     // [T][K][COUT]
    const float* __restrict__ bias,  // [T][COUT]
    float* __restrict__ Y,           // [NPAD][COUT] or d_out [N][COUT]
    const int* __restrict__ meta, const int* __restrict__ perm) {
  const int tn = blockIdx.x, tm = blockIdx.y;
  const int row0 = tm * 64, col0 = tn * 64;
  const int s1 = meta[5], s2 = meta[6], s3 = meta[7];
  const int t = row0 >= s3 ? 3 : (row0 >= s2 ? 2 : (row0 >= s1 ? 1 : 0));
  const float* __restrict__ Wt = W + (size_t)t * K * COUT;

  __shared__ __align__(16) float As[16][68];
  __shared__ __align__(16) float Bs[16][68];

  const int tid = threadIdx.x;
  const int rowA = tid >> 2, kA = (tid & 3) * 4;   // A tile load: 64 rows x 16 k
  const int kB = tid >> 4, colB = (tid & 15) * 4;  // B tile load: 16 k x 64 cols
  const int ty = tid >> 4, tx = tid & 15;          // compute coords

  float acc[4][4] = {};

  for (int k0 = 0; k0 < K; k0 += 16) {
    float4 a4 = *(const float4*)(A + (size_t)(row0 + rowA) * K + k0 + kA);
    float4 b4 = *(const float4*)(Wt + (size_t)(k0 + kB) * COUT + col0 + colB);
    As[kA + 0][rowA] = a4.x;
    As[kA + 1][rowA] = a4.y;
    As[kA + 2][rowA] = a4.z;
    As[kA + 3][rowA] = a4.w;
    *(float4*)&Bs[kB][colB] = b4;
    __syncthreads();
#pragma unroll
    for (int kk = 0; kk < 16; ++kk) {
      float4 av = *(const float4*)&As[kk][ty * 4];
      float4 bv = *(const float4*)&Bs[kk][tx * 4];
      float a[4] = {av.x, av.y, av.z, av.w};
      float b[4] = {bv.x, bv.y, bv.z, bv.w};
#pragma unroll
      for (int i = 0; i < 4; ++i)
#pragma unroll
        for (int j = 0; j < 4; ++j) acc[i][j] = fmaf(a[i], b[j], acc[i][j]);
    }
    __syncthreads();
  }

  float4 bb = *(const float4*)(bias + (size_t)t * COUT + col0 + tx * 4);
#pragma unroll
  for (int i = 0; i < 4; ++i) {
    int r = row0 + ty * 4 + i;
    float4 o = make_float4(acc[i][0] + bb.x, acc[i][1] + bb.y, acc[i][2] + bb.z,
                           acc[i][3] + bb.w);
    if (SCATTER) {
      int dst = perm[r];
      if (dst >= 0) *(float4*)(Y + (size_t)dst * COUT + col0 + tx * 4) = o;
    } else {
      *(float4*)(Y + (size_t)r * COUT + col0 + tx * 4) = o;
    }
  }
}

// ---------------- BN (two-phase deterministic reduction) ----------------

// Phase 1: grid (HDIM/64, NTYPE, NCHUNK). Each block: partial S/Q for 64 cols
// over rows r = chunk*4 + rl + k*NCHUNK*4 (fixed order per thread -> deterministic).
__global__ __launch_bounds__(256) void bn_partial_kernel(const float* __restrict__ h,
                                                         const int* __restrict__ meta,
                                                         float* __restrict__ partS,
                                                         float* __restrict__ partQ) {
  const int t = blockIdx.y;
  const int chunk = blockIdx.z;
  const int lane = threadIdx.x & 63;
  const int rl = threadIdx.x >> 6;  // 0..3
  const int c = blockIdx.x * 64 + lane;
  const int start = meta[4 + t];
  const int cnt = meta[t];
  float s = 0.f, q = 0.f;
  for (int r = chunk * 4 + rl; r < cnt; r += NCHUNK * 4) {
    float v = h[(size_t)(start + r) * HDIM + c];
    s += v;
    q += v * v;
  }
  __shared__ float redS[4][64], redQ[4][64];
  redS[rl][lane] = s;
  redQ[rl][lane] = q;
  __syncthreads();
  if (rl == 0) {
    float S = redS[0][lane] + redS[1][lane] + redS[2][lane] + redS[3][lane];
    float Q = redQ[0][lane] + redQ[1][lane] + redQ[2][lane] + redQ[3][lane];
    size_t o = ((size_t)t * NCHUNK + chunk) * HDIM + c;
    partS[o] = S;
    partQ[o] = Q;
  }
}

// Phase 2: one thread per (t, c); sums NCHUNK partials in fixed order.
__global__ __launch_bounds__(256) void bn_finalize_kernel(const float* __restrict__ partS,
                                                          const float* __restrict__ partQ,
                                                          const int* __restrict__ meta,
                                                          float* __restrict__ mean,
                                                          float* __restrict__ rstd) {
  int idx = blockIdx.x * 256 + threadIdx.x;  // 0 .. NTYPE*HDIM-1
  int t = idx >> 9;                          // / HDIM
  int c = idx & (HDIM - 1);
  float S = 0.f, Q = 0.f;
#pragma unroll 8
  for (int k = 0; k < NCHUNK; ++k) {
    size_t o = ((size_t)t * NCHUNK + k) * HDIM + c;
    S += partS[o];
    Q += partQ[o];
  }
  int cnt = meta[t];
  float n = (float)(cnt > 1 ? cnt : 1);
  float m = S / n;
  float var = Q / n - m * m;
  mean[idx] = m;
  rstd[idx] = rsqrtf(fmaxf(var, 0.f) + BN_EPS);
}

__global__ __launch_bounds__(256) void bn_apply_kernel(
    float* __restrict__ h, const int* __restrict__ meta, const float* __restrict__ mean,
    const float* __restrict__ rstd, const float* __restrict__ gamma,
    const float* __restrict__ beta) {
  size_t idx = (size_t)blockIdx.x * 256 + threadIdx.x;  // float4 units
  int row = (int)(idx >> 7);  // HDIM/4 = 128 float4 per row
  int cq = (int)(idx & 127);
  const int s1 = meta[5], s2 = meta[6], s3 = meta[7];
  const int t = row >= s3 ? 3 : (row >= s2 ? 2 : (row >= s1 ? 1 : 0));
  float4 v = *(float4*)(h + (size_t)row * HDIM + cq * 4);
  float4 m = *(const float4*)(mean + t * HDIM + cq * 4);
  float4 r = *(const float4*)(rstd + t * HDIM + cq * 4);
  float4 g = *(const float4*)(gamma + (size_t)t * HDIM + cq * 4);
  float4 b = *(const float4*)(beta + (size_t)t * HDIM + cq * 4);
  float o0 = (v.x - m.x) * r.x * g.x + b.x;
  float o1 = (v.y - m.y) * r.y * g.y + b.y;
  float o2 = (v.z - m.z) * r.z * g.z + b.z;
  float o3 = (v.w - m.w) * r.w * g.w + b.w;
  o0 = o0 >= 0.f ? o0 : SLOPE * o0;
  o1 = o1 >= 0.f ? o1 : SLOPE * o1;
  o2 = o2 >= 0.f ? o2 : SLOPE * o2;
  o3 = o3 >= 0.f ? o3 : SLOPE * o3;
  *(float4*)(h + (size_t)row * HDIM + cq * 4) = make_float4(o0, o1, o2, o3);
}

// ---------------- launch ----------------

extern "C" void kernel_launch(void* const* d_in, const int* in_sizes, int n_in, void* d_out,
                              int out_size, void* d_ws, size_t ws_size, hipStream_t stream) {
  const float* x = (const float*)d_in[0];
  const int* nt = (const int*)d_in[1];
  const float* W1 = (const float*)d_in[2];
  const float* b1 = (const float*)d_in[3];
  const float* W2 = (const float*)d_in[4];
  const float* b2 = (const float*)d_in[5];
  const float* W3 = (const float*)d_in[6];
  const float* b3 = (const float*)d_in[7];
  const float* g1 = (const float*)d_in[8];
  const float* be1 = (const float*)d_in[9];
  const float* g2 = (const float*)d_in[10];
  const float* be2 = (const float*)d_in[11];
  float* out = (float*)d_out;

  char* ws = (char*)d_ws;
  size_t off = 0;
  auto alloc = [&](size_t bytes) {
    void* p = ws + off;
    off = (off + bytes + 255) & ~(size_t)255;
    return p;
  };
  int* meta = (int*)alloc(16 * 4);
  int* blockHist = (int*)alloc(128 * NTYPE * 4);
  int* blockBase = (int*)alloc(128 * NTYPE * 4);
  int* perm = (int*)alloc((size_t)NPAD * 4);
  float* mean = (float*)alloc((size_t)NTYPE * HDIM * 4);
  float* rstd = (float*)alloc((size_t)NTYPE * HDIM * 4);
  float* partS = (float*)alloc((size_t)NTYPE * NCHUNK * HDIM * 4);
  float* partQ = (float*)alloc((size_t)NTYPE * NCHUNK * HDIM * 4);
  float* bufA = (float*)alloc((size_t)NPAD * HDIM * 4);
  float* bufB = (float*)alloc((size_t)NPAD * HDIM * 4);
  float* xs = bufA;  // [NPAD][CIN]  (first half of bufA)
  float* h1 = bufB;  // [NPAD][HDIM]
  float* h2 = bufA;  // [NPAD][HDIM] (xs is dead by then)

  hipMemsetAsync(meta, 0, 64, stream);
  hipMemsetAsync(perm, 0xFF, (size_t)NPAD * 4, stream);
  hist_kernel<<<128, 256, 0, stream>>>(nt, blockHist);
  scan_kernel<<<1, 64, 0, stream>>>(blockHist, blockBase, meta);
  rank_scatter_kernel<<<128, 256, 0, stream>>>(nt, blockBase, meta, perm);
  gather_kernel<<<NPAD, 64, 0, stream>>>(x, perm, xs);

  gemm_kernel<CIN, HDIM, false>
      <<<dim3(HDIM / 64, NPAD / 64), 256, 0, stream>>>(xs, W1, b1, h1, meta, nullptr);
  bn_partial_kernel<<<dim3(HDIM / 64, NTYPE, NCHUNK), 256, 0, stream>>>(h1, meta, partS, partQ);
  bn_finalize_kernel<<<(NTYPE * HDIM) / 256, 256, 0, stream>>>(partS, partQ, meta, mean, rstd);
  bn_apply_kernel<<<(NPAD * (HDIM / 4)) / 256, 256, 0, stream>>>(h1, meta, mean, rstd, g1, be1);

  gemm_kernel<HDIM, HDIM, false>
      <<<dim3(HDIM / 64, NPAD / 64), 256, 0, stream>>>(h1, W2, b2, h2, meta, nullptr);
  bn_partial_kernel<<<dim3(HDIM / 64, NTYPE, NCHUNK), 256, 0, stream>>>(h2, meta, partS, partQ);
  bn_finalize_kernel<<<(NTYPE * HDIM) / 256, 256, 0, stream>>>(partS, partQ, meta, mean, rstd);
  bn_apply_kernel<<<(NPAD * (HDIM / 4)) / 256, 256, 0, stream>>>(h2, meta, mean, rstd, g2, be2);

  gemm_kernel<HDIM, COUT_F, true>
      <<<dim3(COUT_F / 64, NPAD / 64), 256, 0, stream>>>(h2, W3, b3, out, meta, perm);
}

// Round 3
// 190.075 us; speedup vs baseline: 8.1056x; 3.1165x over previous
//
#include <hip/hip_runtime.h>
#include <cstdint>
#include <cstddef>

#define N_NODES 32768
#define CIN 256
#define HDIM 512
#define COUT_F 256
#define NTYPE 4
#define ALIGN_SEG 128
#define NPAD (N_NODES + NTYPE * ALIGN_SEG)  // 33280
#define BN_EPS 1e-5f
#define SLOPE 0.01f
#define NCHUNK 64

typedef unsigned short u16;
typedef __attribute__((ext_vector_type(8))) short bf16x8;
typedef __attribute__((ext_vector_type(4))) float f32x4;
typedef __attribute__((ext_vector_type(4))) u16 u16x4;

#define GLOBAL_AS __attribute__((address_space(1)))
#define LDS_AS __attribute__((address_space(3)))

__device__ __forceinline__ u16 f2bf(float f) {
  union { float f; unsigned u; } v{f};
  unsigned r = (v.u + 0x7FFF + ((v.u >> 16) & 1)) >> 16;  // RNE, finite inputs
  return (u16)r;
}

// ---------------- sorting machinery ----------------

__global__ void hist_kernel(const int* __restrict__ nt, int* __restrict__ blockHist) {
  __shared__ int h[NTYPE];
  int tid = threadIdx.x;
  if (tid < NTYPE) h[tid] = 0;
  __syncthreads();
  int i = blockIdx.x * 256 + tid;
  atomicAdd(&h[nt[i]], 1);
  __syncthreads();
  if (tid < NTYPE) blockHist[blockIdx.x * NTYPE + tid] = h[tid];
}

__global__ void scan_kernel(const int* __restrict__ blockHist, int* __restrict__ blockBase,
                            int* __restrict__ meta) {
  int tid = threadIdx.x;
  if (tid < NTYPE) {
    int run = 0;
    for (int b = 0; b < 128; ++b) {
      blockBase[b * NTYPE + tid] = run;
      run += blockHist[b * NTYPE + tid];
    }
    meta[tid] = run;  // per-type count
  }
  __syncthreads();
  if (tid == 0) {
    int s = 0;
    for (int t = 0; t < NTYPE; ++t) {
      meta[4 + t] = s;  // aligned segment start
      s += (meta[t] + ALIGN_SEG - 1) & ~(ALIGN_SEG - 1);
    }
    meta[8] = s;  // padded total
  }
}

// stable rank within 256-chunk -> deterministic permutation
__global__ void rank_scatter_kernel(const int* __restrict__ nt, const int* __restrict__ blockBase,
                                    const int* __restrict__ meta, int* __restrict__ perm) {
  __shared__ int st[256];
  int tid = threadIdx.x;
  int i = blockIdx.x * 256 + tid;
  int t = nt[i];
  st[tid] = t;
  __syncthreads();
  int rank = 0;
  for (int j = 0; j < tid; ++j) rank += (st[j] == t) ? 1 : 0;
  perm[meta[4 + t] + blockBase[blockIdx.x * NTYPE + t] + rank] = i;
}

// xs[p] = bf16(x[perm[p]]) (zeros for padding rows). 64 threads: one float4 each.
__global__ void gather_kernel(const float* __restrict__ x, const int* __restrict__ perm,
                              u16* __restrict__ xs) {
  int p = blockIdx.x;
  int src = perm[p];
  u16x4* dst = (u16x4*)(xs + (size_t)p * CIN);
  if (src < 0) {
    dst[threadIdx.x] = (u16x4)0;
  } else {
    float4 v = ((const float4*)(x + (size_t)src * CIN))[threadIdx.x];
    u16x4 o;
    o.x = f2bf(v.x); o.y = f2bf(v.y); o.z = f2bf(v.z); o.w = f2bf(v.w);
    dst[threadIdx.x] = o;
  }
}

// ---------------- weight transpose + bf16 convert ----------------
// W [T][K][COUT] f32  ->  Wt [T][COUT][K] bf16
template <int K, int COUT>
__global__ __launch_bounds__(256) void wtrans_kernel(const float* __restrict__ W,
                                                     u16* __restrict__ Wt) {
  const int t = blockIdx.z;
  const int k0 = blockIdx.x * 32, c0 = blockIdx.y * 32;
  const float* __restrict__ Ws = W + (size_t)t * K * COUT;
  u16* __restrict__ Wd = Wt + (size_t)t * COUT * K;
  __shared__ float tile[32][33];
  int tid = threadIdx.x;
#pragma unroll
  for (int p = 0; p < 4; ++p) {
    int idx = p * 256 + tid;
    int r = idx >> 5, c = idx & 31;
    tile[r][c] = Ws[(size_t)(k0 + r) * COUT + c0 + c];
  }
  __syncthreads();
#pragma unroll
  for (int p = 0; p < 4; ++p) {
    int idx = p * 256 + tid;
    int r = idx >> 5, c = idx & 31;
    Wd[(size_t)(c0 + r) * K + k0 + c] = f2bf(tile[c][r]);
  }
}

// ---------------- bf16 MFMA GEMM ----------------
// 128x128 tile, BK=32, 256 threads = 4 waves (2x2), each wave 4x4 frags of 16x16x32.
// A: [NPAD][K] bf16 (row-major), Bt: [T][COUT][K] bf16 (weights pre-transposed).
// XOR chunk swizzle u = s ^ ((r>>1)&3) applied on the GLOBAL source so LDS is
// written linearly by global_load_lds; ds_read_b128 then hits 2-way banks (free).

template <int K, int COUT, bool SCATTER>
__global__ __launch_bounds__(256) void mfma_gemm_kernel(
    const u16* __restrict__ A, const u16* __restrict__ Wt, const float* __restrict__ bias,
    float* __restrict__ Y, const int* __restrict__ meta, const int* __restrict__ perm) {
  const int col0 = blockIdx.x * 128, row0 = blockIdx.y * 128;
  const int s1 = meta[5], s2 = meta[6], s3 = meta[7];
  const int t = row0 >= s3 ? 3 : (row0 >= s2 ? 2 : (row0 >= s1 ? 1 : 0));
  const u16* __restrict__ Bt = Wt + (size_t)t * COUT * K;

  __shared__ __align__(16) u16 As[128 * 32];
  __shared__ __align__(16) u16 Bs[128 * 32];

  const int tid = threadIdx.x;
  const int wid = tid >> 6, lane = tid & 63;
  const int lr = lane & 15, ls = lane >> 4;  // frag row / k-sub
  const int wm = wid >> 1, wn = wid & 1;

  // fragment LDS element offsets (loop-invariant)
  int a_off[4], b_off[4];
#pragma unroll
  for (int i = 0; i < 4; ++i) {
    int r = wm * 64 + i * 16 + lr;
    a_off[i] = r * 32 + (ls ^ ((r >> 1) & 3)) * 8;
  }
#pragma unroll
  for (int j = 0; j < 4; ++j) {
    int r = wn * 64 + j * 16 + lr;
    b_off[j] = r * 32 + (ls ^ ((r >> 1) & 3)) * 8;
  }

  // staging: chunk c = p*256 + tid; LDS linear at c*16B; global source swizzled
  int st_row[2], st_k[2];
#pragma unroll
  for (int p = 0; p < 2; ++p) {
    int c = p * 256 + tid;
    int r = c >> 2;
    int s = (c & 3) ^ ((r >> 1) & 3);
    st_row[p] = r;
    st_k[p] = s * 8;
  }
  const int lds_base0 = (tid & 192) * 8;  // wave-uniform, elems

  f32x4 acc[4][4] = {};

  for (int k0 = 0; k0 < K; k0 += 32) {
#pragma unroll
    for (int p = 0; p < 2; ++p) {
      const u16* ga = A + (size_t)(row0 + st_row[p]) * K + k0 + st_k[p];
      const u16* gb = Bt + (size_t)(col0 + st_row[p]) * K + k0 + st_k[p];
      u16* la = As + p * 2048 + lds_base0;
      u16* lb = Bs + p * 2048 + lds_base0;
      __builtin_amdgcn_global_load_lds((const GLOBAL_AS void*)ga, (LDS_AS void*)la, 16, 0, 0);
      __builtin_amdgcn_global_load_lds((const GLOBAL_AS void*)gb, (LDS_AS void*)lb, 16, 0, 0);
    }
    __syncthreads();
    bf16x8 af[4], bfr[4];
#pragma unroll
    for (int i = 0; i < 4; ++i) af[i] = *(const bf16x8*)(As + a_off[i]);
#pragma unroll
    for (int j = 0; j < 4; ++j) bfr[j] = *(const bf16x8*)(Bs + b_off[j]);
#pragma unroll
    for (int i = 0; i < 4; ++i)
#pragma unroll
      for (int j = 0; j < 4; ++j)
        acc[i][j] = __builtin_amdgcn_mfma_f32_16x16x32_bf16(af[i], bfr[j], acc[i][j], 0, 0, 0);
    __syncthreads();
  }

  // epilogue: bias add, store fp32. C/D: col = lane&15, row = ls*4 + reg.
  float bj[4];
#pragma unroll
  for (int j = 0; j < 4; ++j) bj[j] = bias[(size_t)t * COUT + col0 + wn * 64 + j * 16 + lr];

#pragma unroll
  for (int i = 0; i < 4; ++i) {
    int rbase = row0 + wm * 64 + i * 16 + ls * 4;
    if (SCATTER) {
      int dsts[4];
#pragma unroll
      for (int r = 0; r < 4; ++r) dsts[r] = perm[rbase + r];
#pragma unroll
      for (int j = 0; j < 4; ++j) {
        int gcol = col0 + wn * 64 + j * 16 + lr;
#pragma unroll
        for (int r = 0; r < 4; ++r) {
          if (dsts[r] >= 0) Y[(size_t)dsts[r] * COUT + gcol] = acc[i][j][r] + bj[j];
        }
      }
    } else {
#pragma unroll
      for (int j = 0; j < 4; ++j) {
        int gcol = col0 + wn * 64 + j * 16 + lr;
#pragma unroll
        for (int r = 0; r < 4; ++r) {
          Y[(size_t)(rbase + r) * COUT + gcol] = acc[i][j][r] + bj[j];
        }
      }
    }
  }
}

// ---------------- BN (two-phase deterministic reduction) ----------------

__global__ __launch_bounds__(256) void bn_partial_kernel(const float* __restrict__ h,
                                                         const int* __restrict__ meta,
                                                         float* __restrict__ partS,
                                                         float* __restrict__ partQ) {
  const int t = blockIdx.y;
  const int chunk = blockIdx.z;
  const int lane = threadIdx.x & 63;
  const int rl = threadIdx.x >> 6;  // 0..3
  const int c = blockIdx.x * 64 + lane;
  const int start = meta[4 + t];
  const int cnt = meta[t];
  float s = 0.f, q = 0.f;
  for (int r = chunk * 4 + rl; r < cnt; r += NCHUNK * 4) {
    float v = h[(size_t)(start + r) * HDIM + c];
    s += v;
    q += v * v;
  }
  __shared__ float redS[4][64], redQ[4][64];
  redS[rl][lane] = s;
  redQ[rl][lane] = q;
  __syncthreads();
  if (rl == 0) {
    float S = redS[0][lane] + redS[1][lane] + redS[2][lane] + redS[3][lane];
    float Q = redQ[0][lane] + redQ[1][lane] + redQ[2][lane] + redQ[3][lane];
    size_t o = ((size_t)t * NCHUNK + chunk) * HDIM + c;
    partS[o] = S;
    partQ[o] = Q;
  }
}

__global__ __launch_bounds__(256) void bn_finalize_kernel(const float* __restrict__ partS,
                                                          const float* __restrict__ partQ,
                                                          const int* __restrict__ meta,
                                                          float* __restrict__ mean,
                                                          float* __restrict__ rstd) {
  int idx = blockIdx.x * 256 + threadIdx.x;  // 0 .. NTYPE*HDIM-1
  int t = idx >> 9;                          // / HDIM
  int c = idx & (HDIM - 1);
  float S = 0.f, Q = 0.f;
#pragma unroll 8
  for (int k = 0; k < NCHUNK; ++k) {
    size_t o = ((size_t)t * NCHUNK + k) * HDIM + c;
    S += partS[o];
    Q += partQ[o];
  }
  int cnt = meta[t];
  float n = (float)(cnt > 1 ? cnt : 1);
  float m = S / n;
  float var = Q / n - m * m;
  mean[idx] = m;
  rstd[idx] = rsqrtf(fmaxf(var, 0.f) + BN_EPS);
}

// normalize + leaky ReLU, emit bf16 activations for the next GEMM
__global__ __launch_bounds__(256) void bn_apply_kernel(
    const float* __restrict__ h, const int* __restrict__ meta, const float* __restrict__ mean,
    const float* __restrict__ rstd, const float* __restrict__ gamma,
    const float* __restrict__ beta, u16* __restrict__ aout) {
  size_t idx = (size_t)blockIdx.x * 256 + threadIdx.x;  // float4 units
  int row = (int)(idx >> 7);  // HDIM/4 = 128 float4 per row
  int cq = (int)(idx & 127);
  const int s1 = meta[5], s2 = meta[6], s3 = meta[7];
  const int t = row >= s3 ? 3 : (row >= s2 ? 2 : (row >= s1 ? 1 : 0));
  float4 v = *(const float4*)(h + (size_t)row * HDIM + cq * 4);
  float4 m = *(const float4*)(mean + t * HDIM + cq * 4);
  float4 r = *(const float4*)(rstd + t * HDIM + cq * 4);
  float4 g = *(const float4*)(gamma + (size_t)t * HDIM + cq * 4);
  float4 b = *(const float4*)(beta + (size_t)t * HDIM + cq * 4);
  float o0 = (v.x - m.x) * r.x * g.x + b.x;
  float o1 = (v.y - m.y) * r.y * g.y + b.y;
  float o2 = (v.z - m.z) * r.z * g.z + b.z;
  float o3 = (v.w - m.w) * r.w * g.w + b.w;
  o0 = o0 >= 0.f ? o0 : SLOPE * o0;
  o1 = o1 >= 0.f ? o1 : SLOPE * o1;
  o2 = o2 >= 0.f ? o2 : SLOPE * o2;
  o3 = o3 >= 0.f ? o3 : SLOPE * o3;
  u16x4 o;
  o.x = f2bf(o0); o.y = f2bf(o1); o.z = f2bf(o2); o.w = f2bf(o3);
  *(u16x4*)(aout + (size_t)row * HDIM + cq * 4) = o;
}

// ---------------- launch ----------------

extern "C" void kernel_launch(void* const* d_in, const int* in_sizes, int n_in, void* d_out,
                              int out_size, void* d_ws, size_t ws_size, hipStream_t stream) {
  const float* x = (const float*)d_in[0];
  const int* nt = (const int*)d_in[1];
  const float* W1 = (const float*)d_in[2];
  const float* b1 = (const float*)d_in[3];
  const float* W2 = (const float*)d_in[4];
  const float* b2 = (const float*)d_in[5];
  const float* W3 = (const float*)d_in[6];
  const float* b3 = (const float*)d_in[7];
  const float* g1 = (const float*)d_in[8];
  const float* be1 = (const float*)d_in[9];
  const float* g2 = (const float*)d_in[10];
  const float* be2 = (const float*)d_in[11];
  float* out = (float*)d_out;

  char* ws = (char*)d_ws;
  size_t off = 0;
  auto alloc = [&](size_t bytes) {
    void* p = ws + off;
    off = (off + bytes + 255) & ~(size_t)255;
    return p;
  };
  int* meta = (int*)alloc(16 * 4);
  int* blockHist = (int*)alloc(128 * NTYPE * 4);
  int* blockBase = (int*)alloc(128 * NTYPE * 4);
  int* perm = (int*)alloc((size_t)NPAD * 4);
  float* mean = (float*)alloc((size_t)NTYPE * HDIM * 4);
  float* rstd = (float*)alloc((size_t)NTYPE * HDIM * 4);
  float* partS = (float*)alloc((size_t)NTYPE * NCHUNK * HDIM * 4);
  float* partQ = (float*)alloc((size_t)NTYPE * NCHUNK * HDIM * 4);
  u16* Wt1 = (u16*)alloc((size_t)NTYPE * CIN * HDIM * 2);
  u16* Wt2 = (u16*)alloc((size_t)NTYPE * HDIM * HDIM * 2);
  u16* Wt3 = (u16*)alloc((size_t)NTYPE * HDIM * COUT_F * 2);
  u16* xs = (u16*)alloc((size_t)NPAD * CIN * 2);     // bf16 layer-1 input
  u16* abuf = (u16*)alloc((size_t)NPAD * HDIM * 2);  // bf16 activations
  float* hbuf = (float*)alloc((size_t)NPAD * HDIM * 4);  // fp32 pre-BN

  hipMemsetAsync(meta, 0, 64, stream);
  hipMemsetAsync(perm, 0xFF, (size_t)NPAD * 4, stream);
  hist_kernel<<<128, 256, 0, stream>>>(nt, blockHist);
  scan_kernel<<<1, 64, 0, stream>>>(blockHist, blockBase, meta);
  rank_scatter_kernel<<<128, 256, 0, stream>>>(nt, blockBase, meta, perm);
  gather_kernel<<<NPAD, 64, 0, stream>>>(x, perm, xs);

  wtrans_kernel<CIN, HDIM><<<dim3(CIN / 32, HDIM / 32, NTYPE), 256, 0, stream>>>(W1, Wt1);
  wtrans_kernel<HDIM, HDIM><<<dim3(HDIM / 32, HDIM / 32, NTYPE), 256, 0, stream>>>(W2, Wt2);
  wtrans_kernel<HDIM, COUT_F><<<dim3(HDIM / 32, COUT_F / 32, NTYPE), 256, 0, stream>>>(W3, Wt3);

  // Layer 1
  mfma_gemm_kernel<CIN, HDIM, false>
      <<<dim3(HDIM / 128, NPAD / 128), 256, 0, stream>>>(xs, Wt1, b1, hbuf, meta, nullptr);
  bn_partial_kernel<<<dim3(HDIM / 64, NTYPE, NCHUNK), 256, 0, stream>>>(hbuf, meta, partS, partQ);
  bn_finalize_kernel<<<(NTYPE * HDIM) / 256, 256, 0, stream>>>(partS, partQ, meta, mean, rstd);
  bn_apply_kernel<<<(NPAD * (HDIM / 4)) / 256, 256, 0, stream>>>(hbuf, meta, mean, rstd, g1, be1,
                                                                 abuf);
  // Layer 2
  mfma_gemm_kernel<HDIM, HDIM, false>
      <<<dim3(HDIM / 128, NPAD / 128), 256, 0, stream>>>(abuf, Wt2, b2, hbuf, meta, nullptr);
  bn_partial_kernel<<<dim3(HDIM / 64, NTYPE, NCHUNK), 256, 0, stream>>>(hbuf, meta, partS, partQ);
  bn_finalize_kernel<<<(NTYPE * HDIM) / 256, 256, 0, stream>>>(partS, partQ, meta, mean, rstd);
  bn_apply_kernel<<<(NPAD * (HDIM / 4)) / 256, 256, 0, stream>>>(hbuf, meta, mean, rstd, g2, be2,
                                                                 abuf);
  // Layer 3 (scatter to d_out)
  mfma_gemm_kernel<HDIM, COUT_F, true>
      <<<dim3(COUT_F / 128, NPAD / 128), 256, 0, stream>>>(abuf, Wt3, b3, out, meta, perm);
}